// Round 4
// baseline (70.230 us; speedup 1.0000x reference)
//
#include <hip/hip_runtime.h>
#include <math.h>

constexpr int H = 2048;
constexpr int W = 4096;
constexpr int RS = W * 3;   // floats per image row

// Keys cubic (a = -0.5) pieces on known-positive argument.
__device__ __forceinline__ float k_inner(float t) {   // t in [0,1]:  1.5t^3 - 2.5t^2 + 1
    return fmaf(fmaf(1.5f, t, -2.5f), t * t, 1.0f);
}
__device__ __forceinline__ float k_outer(float t) {   // t in [1,2]: -0.5t^3 + 2.5t^2 - 4t + 2
    return fmaf(fmaf(fmaf(-0.5f, t, 2.5f), t, -4.0f), t, 2.0f);
}
__device__ __forceinline__ float cubic_w(float t) {
    float at = fabsf(t);
    if (at <= 1.0f) return k_inner(at);
    if (at < 2.0f)  return k_outer(at);
    return 0.0f;
}

// accumulate one row of 4 taps x 3 channels from 3 float4s (12 contiguous floats)
#define ROWACC(va, vb, vc, q0, q1, q2, q3, A0, A1, A2)                              \
    A0 = fmaf(q0, va.x, fmaf(q1, va.w, fmaf(q2, vb.z, fmaf(q3, vc.y, A0))));        \
    A1 = fmaf(q0, va.y, fmaf(q1, vb.x, fmaf(q2, vb.w, fmaf(q3, vc.z, A1))));        \
    A2 = fmaf(q0, va.z, fmaf(q1, vb.y, fmaf(q2, vc.x, fmaf(q3, vc.w, A2))));

__global__ __launch_bounds__(256)
void elastic_warp_kernel(const float* __restrict__ img,
                         const float* __restrict__ dctrl,  // (2,3,3) unscaled
                         float* __restrict__ out) {
    // Block: 256 consecutive w, 2 consecutive rows. Each thread -> pixels (h0,w),(h0+1,w)
    int h0 = (blockIdx.x >> 4) * 2;
    int w  = ((blockIdx.x & 15) << 8) | threadIdx.x;

    // Block-uniform: cy = 5*(by^T . D) for both rows: [row][{dy0..2,dx0..2}]
    __shared__ float s_cy[12];
    if (threadIdx.x < 2) {
        int h = h0 + (int)threadIdx.x;
        float u = (float)(2 * h) / (float)(H - 1);
        float i0 = floorf(u);
        float by0 = 0.0f, by1 = 0.0f, by2 = 0.0f;
#pragma unroll
        for (int k = -1; k < 3; ++k) {
            float tap = i0 + (float)k;
            float wt = cubic_w(u - tap);
            int tc = (int)tap;
            tc = tc < 0 ? 0 : (tc > 2 ? 2 : tc);
            if (tc == 0) by0 += wt; else if (tc == 1) by1 += wt; else by2 += wt;
        }
        float* cy = s_cy + threadIdx.x * 6;
#pragma unroll
        for (int x = 0; x < 3; ++x) {
            cy[x]     = 5.0f * (by0 * dctrl[x]     + by1 * dctrl[3 + x]  + by2 * dctrl[6 + x]);
            cy[3 + x] = 5.0f * (by0 * dctrl[9 + x] + by1 * dctrl[12 + x] + by2 * dctrl[15 + x]);
        }
    }
    __syncthreads();

    // per-thread bx (shared by both pixels; same w)
    float u = (float)w * (2.0f / 4095.0f);
    bool hiu = u >= 1.0f;
    float s = u - (hiu ? 1.0f : 0.0f);
    float o1 = k_outer(1.0f + s);
    float is = k_inner(s);
    float i1 = k_inner(1.0f - s);
    float o2 = k_outer(2.0f - s);
    float bx0 = hiu ? o1 : (o1 + is);
    float bx1 = hiu ? is : i1;
    float bx2 = hiu ? (i1 + o2) : o2;

    float d0a = s_cy[0] * bx0 + s_cy[1] * bx1 + s_cy[2]  * bx2;
    float d1a = s_cy[3] * bx0 + s_cy[4] * bx1 + s_cy[5]  * bx2;
    float d0b = s_cy[6] * bx0 + s_cy[7] * bx1 + s_cy[8]  * bx2;
    float d1b = s_cy[9] * bx0 + s_cy[10] * bx1 + s_cy[11] * bx2;

    float yy0 = (float)h0 + d0a,        xx0 = (float)w + d1a;
    float yy1 = (float)(h0 + 1) + d0b,  xx1 = (float)w + d1b;
    float fl_y0 = floorf(yy0), fl_x0 = floorf(xx0);
    float fl_y1 = floorf(yy1), fl_x1 = floorf(xx1);
    float fy0 = yy0 - fl_y0, fx0 = xx0 - fl_x0;
    float fy1 = yy1 - fl_y1, fx1 = xx1 - fl_x1;
    int iy0 = (int)fl_y0, ix0 = (int)fl_x0;
    int iy1 = (int)fl_y1, ix1 = (int)fl_x1;

    float wy0[4] = {k_outer(1.0f + fy0), k_inner(fy0), k_inner(1.0f - fy0), k_outer(2.0f - fy0)};
    float wy1[4] = {k_outer(1.0f + fy1), k_inner(fy1), k_inner(1.0f - fy1), k_outer(2.0f - fy1)};
    float wxa[4] = {k_outer(1.0f + fx0), k_inner(fx0), k_inner(1.0f - fx0), k_outer(2.0f - fx0)};
    float wxb[4] = {k_outer(1.0f + fx1), k_inner(fx1), k_inner(1.0f - fx1), k_outer(2.0f - fx1)};

    float a0 = 0.f, a1 = 0.f, a2 = 0.f;   // pixel (h0, w)
    float b0 = 0.f, b1 = 0.f, b2 = 0.f;   // pixel (h0+1, w)

    // fast: shared x-window, contiguous 5-row union, fully interior
    bool fast = (iy1 == iy0 + 1) & (ix1 == ix0) &
                (iy0 >= 1) & (iy0 <= H - 4) & (ix0 >= 1) & (ix0 <= W - 3);

    if (fast) {
        int off = ((iy0 - 1) * W + (ix0 - 1)) * 3;
        const float* base = img + off;
        const float4* r0 = (const float4*)(base);
        const float4* r1 = (const float4*)(base + RS);
        const float4* r2 = (const float4*)(base + 2 * RS);
        const float4* r3 = (const float4*)(base + 3 * RS);
        const float4* r4 = (const float4*)(base + 4 * RS);
        float4 v0a = r0[0], v0b = r0[1], v0c = r0[2];
        float4 v1a = r1[0], v1b = r1[1], v1c = r1[2];
        float4 v2a = r2[0], v2b = r2[1], v2c = r2[2];
        float4 v3a = r3[0], v3b = r3[1], v3c = r3[2];
        float4 v4a = r4[0], v4b = r4[1], v4c = r4[2];

        // px0: union rows 0..3
        { float q0=wy0[0]*wxa[0], q1=wy0[0]*wxa[1], q2=wy0[0]*wxa[2], q3=wy0[0]*wxa[3];
          ROWACC(v0a, v0b, v0c, q0, q1, q2, q3, a0, a1, a2) }
        { float q0=wy0[1]*wxa[0], q1=wy0[1]*wxa[1], q2=wy0[1]*wxa[2], q3=wy0[1]*wxa[3];
          ROWACC(v1a, v1b, v1c, q0, q1, q2, q3, a0, a1, a2) }
        { float q0=wy0[2]*wxa[0], q1=wy0[2]*wxa[1], q2=wy0[2]*wxa[2], q3=wy0[2]*wxa[3];
          ROWACC(v2a, v2b, v2c, q0, q1, q2, q3, a0, a1, a2) }
        { float q0=wy0[3]*wxa[0], q1=wy0[3]*wxa[1], q2=wy0[3]*wxa[2], q3=wy0[3]*wxa[3];
          ROWACC(v3a, v3b, v3c, q0, q1, q2, q3, a0, a1, a2) }
        // px1: union rows 1..4
        { float q0=wy1[0]*wxb[0], q1=wy1[0]*wxb[1], q2=wy1[0]*wxb[2], q3=wy1[0]*wxb[3];
          ROWACC(v1a, v1b, v1c, q0, q1, q2, q3, b0, b1, b2) }
        { float q0=wy1[1]*wxb[0], q1=wy1[1]*wxb[1], q2=wy1[1]*wxb[2], q3=wy1[1]*wxb[3];
          ROWACC(v2a, v2b, v2c, q0, q1, q2, q3, b0, b1, b2) }
        { float q0=wy1[2]*wxb[0], q1=wy1[2]*wxb[1], q2=wy1[2]*wxb[2], q3=wy1[2]*wxb[3];
          ROWACC(v3a, v3b, v3c, q0, q1, q2, q3, b0, b1, b2) }
        { float q0=wy1[3]*wxb[0], q1=wy1[3]*wxb[1], q2=wy1[3]*wxb[2], q3=wy1[3]*wxb[3];
          ROWACC(v4a, v4b, v4c, q0, q1, q2, q3, b0, b1, b2) }
    } else {
        // fully general clamped gather for both pixels (rare lanes)
#pragma unroll
        for (int a = 0; a < 4; ++a) {
            int ty = iy0 + a - 1;
            ty = ty < 0 ? 0 : (ty > H - 1 ? H - 1 : ty);
            int rowoff = ty * RS;
            float ay = wy0[a];
#pragma unroll
            for (int b = 0; b < 4; ++b) {
                int tx = ix0 + b - 1;
                tx = tx < 0 ? 0 : (tx > W - 1 ? W - 1 : tx);
                float wgt = ay * wxa[b];
                const float* p = img + rowoff + tx * 3;
                a0 += wgt * p[0]; a1 += wgt * p[1]; a2 += wgt * p[2];
            }
        }
#pragma unroll
        for (int a = 0; a < 4; ++a) {
            int ty = iy1 + a - 1;
            ty = ty < 0 ? 0 : (ty > H - 1 ? H - 1 : ty);
            int rowoff = ty * RS;
            float ay = wy1[a];
#pragma unroll
            for (int b = 0; b < 4; ++b) {
                int tx = ix1 + b - 1;
                tx = tx < 0 ? 0 : (tx > W - 1 ? W - 1 : tx);
                float wgt = ay * wxb[b];
                const float* p = img + rowoff + tx * 3;
                b0 += wgt * p[0]; b1 += wgt * p[1]; b2 += wgt * p[2];
            }
        }
    }

    int o0 = (h0 * W + w) * 3;
    out[o0]          = a0;
    out[o0 + 1]      = a1;
    out[o0 + 2]      = a2;
    out[o0 + RS]     = b0;
    out[o0 + RS + 1] = b1;
    out[o0 + RS + 2] = b2;
}

extern "C" void kernel_launch(void* const* d_in, const int* in_sizes, int n_in,
                              void* d_out, int out_size, void* d_ws, size_t ws_size,
                              hipStream_t stream) {
    const float* img   = (const float*)d_in[0];
    const float* dctrl = (const float*)d_in[1];
    float* out = (float*)d_out;

    // (H/2) row-pairs x (W/256) column tiles
    int blocks = (H / 2) * (W / 256);
    elastic_warp_kernel<<<blocks, 256, 0, stream>>>(img, dctrl, out);
}

// Round 5
// 66.851 us; speedup vs baseline: 1.0505x; 1.0505x over previous
//
#include <hip/hip_runtime.h>
#include <math.h>

constexpr int H = 2048;
constexpr int W = 4096;
constexpr int RS = W * 3;   // floats per image row

// Keys cubic (a = -0.5) pieces on known-positive argument.
__device__ __forceinline__ float k_inner(float t) {   // t in [0,1]:  1.5t^3 - 2.5t^2 + 1
    return fmaf(fmaf(1.5f, t, -2.5f), t * t, 1.0f);
}
__device__ __forceinline__ float k_outer(float t) {   // t in [1,2]: -0.5t^3 + 2.5t^2 - 4t + 2
    return fmaf(fmaf(fmaf(-0.5f, t, 2.5f), t, -4.0f), t, 2.0f);
}
__device__ __forceinline__ float cubic_w(float t) {
    float at = fabsf(t);
    if (at <= 1.0f) return k_inner(at);
    if (at < 2.0f)  return k_outer(at);
    return 0.0f;
}

__global__ __launch_bounds__(256, 4)
void elastic_warp_kernel(const float* __restrict__ img,
                         const float* __restrict__ dctrl,  // (2,3,3) unscaled
                         float* __restrict__ out) {
    // Each block covers 256 consecutive pixels of ONE row (W/256 = 16 blocks/row)
    int h = blockIdx.x >> 4;
    int w = ((blockIdx.x & 15) << 8) | threadIdx.x;

    // ---- block-uniform: cy = 5 * (by^T . D) ----
    __shared__ float s_cy[6];
    if (threadIdx.x == 0) {
        float u = (float)(2 * h) / (float)(H - 1);
        float i0 = floorf(u);
        float by0 = 0.0f, by1 = 0.0f, by2 = 0.0f;
#pragma unroll
        for (int k = -1; k < 3; ++k) {
            float tap = i0 + (float)k;
            float wt = cubic_w(u - tap);
            int tc = (int)tap;
            tc = tc < 0 ? 0 : (tc > 2 ? 2 : tc);
            if (tc == 0) by0 += wt; else if (tc == 1) by1 += wt; else by2 += wt;
        }
#pragma unroll
        for (int x = 0; x < 3; ++x) {
            s_cy[x]     = 5.0f * (by0 * dctrl[x]     + by1 * dctrl[3 + x]  + by2 * dctrl[6 + x]);
            s_cy[3 + x] = 5.0f * (by0 * dctrl[9 + x] + by1 * dctrl[12 + x] + by2 * dctrl[15 + x]);
        }
    }
    __syncthreads();

    // ---- per-thread bx[3] (piecewise, branchless) ----
    float u = (float)w * (2.0f / 4095.0f);
    bool hiu = u >= 1.0f;
    float s = u - (hiu ? 1.0f : 0.0f);
    float o1 = k_outer(1.0f + s);
    float is = k_inner(s);
    float i1 = k_inner(1.0f - s);
    float o2 = k_outer(2.0f - s);
    float bx0 = hiu ? o1 : (o1 + is);
    float bx1 = hiu ? is : i1;
    float bx2 = hiu ? (i1 + o2) : o2;

    float d0 = s_cy[0] * bx0 + s_cy[1] * bx1 + s_cy[2] * bx2;
    float d1 = s_cy[3] * bx0 + s_cy[4] * bx1 + s_cy[5] * bx2;

    // ---- sample coordinates & tap weights ----
    float yy = (float)h + d0;
    float xx = (float)w + d1;
    float iy0f = floorf(yy);
    float ix0f = floorf(xx);
    float fy = yy - iy0f;
    float fx = xx - ix0f;
    int iy0 = (int)iy0f;
    int ix0 = (int)ix0f;

    float wy0 = k_outer(1.0f + fy), wy1 = k_inner(fy), wy2 = k_inner(1.0f - fy), wy3 = k_outer(2.0f - fy);
    float wx0 = k_outer(1.0f + fx), wx1 = k_inner(fx), wx2 = k_inner(1.0f - fx), wx3 = k_outer(2.0f - fx);
    float wy[4] = {wy0, wy1, wy2, wy3};

    float acc0 = 0.0f, acc1 = 0.0f, acc2 = 0.0f;

    bool interior = (iy0 >= 1) & (iy0 <= H - 3) & (ix0 >= 1) & (ix0 <= W - 3);
    if (interior) {
        int off = ((iy0 - 1) * W + (ix0 - 1)) * 3;

        // All 12 loads issued before any accumulation (statically indexed array
        // -> registers; launch_bounds(256,4) gives the allocator room to keep
        // them all live -> 12 outstanding vmem ops per wave).
        float4 v[4][3];
#pragma unroll
        for (int a = 0; a < 4; ++a) {
            const float4* p = (const float4*)(img + off + a * RS);
            v[a][0] = p[0];
            v[a][1] = p[1];
            v[a][2] = p[2];
        }

#pragma unroll
        for (int a = 0; a < 4; ++a) {
            float q0 = wy[a] * wx0, q1 = wy[a] * wx1, q2 = wy[a] * wx2, q3 = wy[a] * wx3;
            float4 va = v[a][0], vb = v[a][1], vc = v[a][2];
            acc0 = fmaf(q0, va.x, fmaf(q1, va.w, fmaf(q2, vb.z, fmaf(q3, vc.y, acc0))));
            acc1 = fmaf(q0, va.y, fmaf(q1, vb.x, fmaf(q2, vb.w, fmaf(q3, vc.z, acc1))));
            acc2 = fmaf(q0, va.z, fmaf(q1, vb.y, fmaf(q2, vc.x, fmaf(q3, vc.w, acc2))));
        }
    } else {
        float wx[4] = {wx0, wx1, wx2, wx3};
#pragma unroll
        for (int a = 0; a < 4; ++a) {
            int ty = iy0 + a - 1;
            ty = ty < 0 ? 0 : (ty > H - 1 ? H - 1 : ty);
            int rowoff = ty * RS;
            float ay = wy[a];
#pragma unroll
            for (int b = 0; b < 4; ++b) {
                int tx = ix0 + b - 1;
                tx = tx < 0 ? 0 : (tx > W - 1 ? W - 1 : tx);
                float wgt = ay * wx[b];
                const float* p = img + rowoff + tx * 3;
                acc0 += wgt * p[0];
                acc1 += wgt * p[1];
                acc2 += wgt * p[2];
            }
        }
    }

    int oo = (blockIdx.x * 256 + threadIdx.x) * 3;
    out[oo + 0] = acc0;
    out[oo + 1] = acc1;
    out[oo + 2] = acc2;
}

extern "C" void kernel_launch(void* const* d_in, const int* in_sizes, int n_in,
                              void* d_out, int out_size, void* d_ws, size_t ws_size,
                              hipStream_t stream) {
    const float* img   = (const float*)d_in[0];
    const float* dctrl = (const float*)d_in[1];
    float* out = (float*)d_out;

    int blocks = (H * W) / 256;
    elastic_warp_kernel<<<blocks, 256, 0, stream>>>(img, dctrl, out);
}

// Round 6
// 65.372 us; speedup vs baseline: 1.0743x; 1.0226x over previous
//
#include <hip/hip_runtime.h>
#include <math.h>

constexpr int H = 2048;
constexpr int W = 4096;
constexpr int RS = W * 3;   // floats per image row

// Keys cubic (a = -0.5) pieces on known-positive argument.
__device__ __forceinline__ float k_inner(float t) {   // t in [0,1]:  1.5t^3 - 2.5t^2 + 1
    return fmaf(fmaf(1.5f, t, -2.5f), t * t, 1.0f);
}
__device__ __forceinline__ float k_outer(float t) {   // t in [1,2]: -0.5t^3 + 2.5t^2 - 4t + 2
    return fmaf(fmaf(fmaf(-0.5f, t, 2.5f), t, -4.0f), t, 2.0f);
}
__device__ __forceinline__ float cubic_w(float t) {
    float at = fabsf(t);
    if (at <= 1.0f) return k_inner(at);
    if (at < 2.0f)  return k_outer(at);
    return 0.0f;
}

__global__ __launch_bounds__(256, 4)
void elastic_warp_kernel(const float* __restrict__ img,
                         const float* __restrict__ dctrl,  // (2,3,3) unscaled
                         float* __restrict__ out) {
    // Each block covers 256 consecutive pixels of ONE row (W/256 = 16 blocks/row)
    int h = blockIdx.x >> 4;
    int w = ((blockIdx.x & 15) << 8) | threadIdx.x;

    // ---- block-uniform: cy = 5 * (by^T . D) ----
    __shared__ float s_cy[6];
    if (threadIdx.x == 0) {
        float u = (float)(2 * h) / (float)(H - 1);
        float i0 = floorf(u);
        float by0 = 0.0f, by1 = 0.0f, by2 = 0.0f;
#pragma unroll
        for (int k = -1; k < 3; ++k) {
            float tap = i0 + (float)k;
            float wt = cubic_w(u - tap);
            int tc = (int)tap;
            tc = tc < 0 ? 0 : (tc > 2 ? 2 : tc);
            if (tc == 0) by0 += wt; else if (tc == 1) by1 += wt; else by2 += wt;
        }
#pragma unroll
        for (int x = 0; x < 3; ++x) {
            s_cy[x]     = 5.0f * (by0 * dctrl[x]     + by1 * dctrl[3 + x]  + by2 * dctrl[6 + x]);
            s_cy[3 + x] = 5.0f * (by0 * dctrl[9 + x] + by1 * dctrl[12 + x] + by2 * dctrl[15 + x]);
        }
    }
    __syncthreads();

    float cy0 = s_cy[0], cy1 = s_cy[1], cy2 = s_cy[2];
    float cy3 = s_cy[3], cy4 = s_cy[4], cy5 = s_cy[5];

    // ---- per-thread bx[3] (piecewise, branchless) ----
    float u = (float)w * (2.0f / 4095.0f);
    bool hiu = u >= 1.0f;
    float s = u - (hiu ? 1.0f : 0.0f);
    float o1 = k_outer(1.0f + s);
    float is = k_inner(s);
    float i1 = k_inner(1.0f - s);
    float o2 = k_outer(2.0f - s);
    float bx0 = hiu ? o1 : (o1 + is);
    float bx1 = hiu ? is : i1;
    float bx2 = hiu ? (i1 + o2) : o2;

    float d0 = cy0 * bx0 + cy1 * bx1 + cy2 * bx2;
    float d1 = cy3 * bx0 + cy4 * bx1 + cy5 * bx2;

    // ---- sample coordinates ----
    float yy = (float)h + d0;
    float xx = (float)w + d1;
    float iy0f = floorf(yy);
    float ix0f = floorf(xx);
    float fy = yy - iy0f;
    float fx = xx - ix0f;
    int iy0 = (int)iy0f;
    int ix0 = (int)ix0f;

    float acc0 = 0.0f, acc1 = 0.0f, acc2 = 0.0f;

    bool interior = (iy0 >= 1) & (iy0 <= H - 3) & (ix0 >= 1) & (ix0 <= W - 3);
    if (interior) {
        int off = ((iy0 - 1) * W + (ix0 - 1)) * 3;
        const float* b0 = img + off;
        const float* b1 = b0 + RS;
        const float* b2 = b1 + RS;
        const float* b3 = b2 + RS;

        // ---- issue ALL 12 loads, then hard-fence the scheduler so nothing
        // (and no register reuse) moves across: forces 12 outstanding vmem ----
        float4 v00 = ((const float4*)b0)[0];
        float4 v01 = ((const float4*)b0)[1];
        float4 v02 = ((const float4*)b0)[2];
        float4 v10 = ((const float4*)b1)[0];
        float4 v11 = ((const float4*)b1)[1];
        float4 v12 = ((const float4*)b1)[2];
        float4 v20 = ((const float4*)b2)[0];
        float4 v21 = ((const float4*)b2)[1];
        float4 v22 = ((const float4*)b2)[2];
        float4 v30 = ((const float4*)b3)[0];
        float4 v31 = ((const float4*)b3)[1];
        float4 v32 = ((const float4*)b3)[2];
        __builtin_amdgcn_sched_barrier(0);

        // ---- weight math AFTER load issue: overlaps the memory latency ----
        float wy0 = k_outer(1.0f + fy), wy1 = k_inner(fy), wy2 = k_inner(1.0f - fy), wy3 = k_outer(2.0f - fy);
        float wx0 = k_outer(1.0f + fx), wx1 = k_inner(fx), wx2 = k_inner(1.0f - fx), wx3 = k_outer(2.0f - fx);

        float q0, q1, q2, q3;
        q0 = wy0 * wx0; q1 = wy0 * wx1; q2 = wy0 * wx2; q3 = wy0 * wx3;
        acc0 = fmaf(q0, v00.x, fmaf(q1, v00.w, fmaf(q2, v01.z, fmaf(q3, v02.y, acc0))));
        acc1 = fmaf(q0, v00.y, fmaf(q1, v01.x, fmaf(q2, v01.w, fmaf(q3, v02.z, acc1))));
        acc2 = fmaf(q0, v00.z, fmaf(q1, v01.y, fmaf(q2, v02.x, fmaf(q3, v02.w, acc2))));

        q0 = wy1 * wx0; q1 = wy1 * wx1; q2 = wy1 * wx2; q3 = wy1 * wx3;
        acc0 = fmaf(q0, v10.x, fmaf(q1, v10.w, fmaf(q2, v11.z, fmaf(q3, v12.y, acc0))));
        acc1 = fmaf(q0, v10.y, fmaf(q1, v11.x, fmaf(q2, v11.w, fmaf(q3, v12.z, acc1))));
        acc2 = fmaf(q0, v10.z, fmaf(q1, v11.y, fmaf(q2, v12.x, fmaf(q3, v12.w, acc2))));

        q0 = wy2 * wx0; q1 = wy2 * wx1; q2 = wy2 * wx2; q3 = wy2 * wx3;
        acc0 = fmaf(q0, v20.x, fmaf(q1, v20.w, fmaf(q2, v21.z, fmaf(q3, v22.y, acc0))));
        acc1 = fmaf(q0, v20.y, fmaf(q1, v21.x, fmaf(q2, v21.w, fmaf(q3, v22.z, acc1))));
        acc2 = fmaf(q0, v20.z, fmaf(q1, v21.y, fmaf(q2, v22.x, fmaf(q3, v22.w, acc2))));

        q0 = wy3 * wx0; q1 = wy3 * wx1; q2 = wy3 * wx2; q3 = wy3 * wx3;
        acc0 = fmaf(q0, v30.x, fmaf(q1, v30.w, fmaf(q2, v31.z, fmaf(q3, v32.y, acc0))));
        acc1 = fmaf(q0, v30.y, fmaf(q1, v31.x, fmaf(q2, v31.w, fmaf(q3, v32.z, acc1))));
        acc2 = fmaf(q0, v30.z, fmaf(q1, v31.y, fmaf(q2, v32.x, fmaf(q3, v32.w, acc2))));
    } else {
        float wy[4] = {k_outer(1.0f + fy), k_inner(fy), k_inner(1.0f - fy), k_outer(2.0f - fy)};
        float wx[4] = {k_outer(1.0f + fx), k_inner(fx), k_inner(1.0f - fx), k_outer(2.0f - fx)};
#pragma unroll
        for (int a = 0; a < 4; ++a) {
            int ty = iy0 + a - 1;
            ty = ty < 0 ? 0 : (ty > H - 1 ? H - 1 : ty);
            int rowoff = ty * RS;
            float ay = wy[a];
#pragma unroll
            for (int b = 0; b < 4; ++b) {
                int tx = ix0 + b - 1;
                tx = tx < 0 ? 0 : (tx > W - 1 ? W - 1 : tx);
                float wgt = ay * wx[b];
                const float* p = img + rowoff + tx * 3;
                acc0 += wgt * p[0];
                acc1 += wgt * p[1];
                acc2 += wgt * p[2];
            }
        }
    }

    int oo = (blockIdx.x * 256 + threadIdx.x) * 3;
    out[oo + 0] = acc0;
    out[oo + 1] = acc1;
    out[oo + 2] = acc2;
}

extern "C" void kernel_launch(void* const* d_in, const int* in_sizes, int n_in,
                              void* d_out, int out_size, void* d_ws, size_t ws_size,
                              hipStream_t stream) {
    const float* img   = (const float*)d_in[0];
    const float* dctrl = (const float*)d_in[1];
    float* out = (float*)d_out;

    int blocks = (H * W) / 256;
    elastic_warp_kernel<<<blocks, 256, 0, stream>>>(img, dctrl, out);
}